// Round 8
// baseline (529.219 us; speedup 1.0000x reference)
//
#include <hip/hip_runtime.h>
#include <hip/hip_cooperative_groups.h>

// Mamba block fused pipeline, MI355X gfx950.
// B=1, L=2048, D_MODEL=1024, D_INNER=2048, D_CONV=4, DT_RANK=64, D_STATE=16.
//
// R8: R7's cooperative fused scan retained but with a runtime fallback: if
// hipLaunchCooperativeKernel errors (R7 hard-failed here: ygb never written,
// out ~= 0), launch the proven 3-kernel scan (same math/buffers). xin stored
// bf16 by G1 (conv reads bf16, 4 timesteps/thread) -> ~24 MB less traffic.

#define L_SEQ 2048
#define DMODEL 1024
#define DINNER 2048
#define NSTATE 16
#define DTRANK 64
#define NPROJ_PAD 128
#define NCH 128
#define TCH 16

namespace cg = cooperative_groups;

typedef __attribute__((ext_vector_type(8))) short short8;
typedef __attribute__((ext_vector_type(4))) float f32x4;

__device__ __forceinline__ unsigned short f2bf(float f) {
  unsigned int u = __float_as_uint(f);
  u += 0x7FFFu + ((u >> 16) & 1u);  // round-to-nearest-even
  return (unsigned short)(u >> 16);
}
__device__ __forceinline__ float bf2f(unsigned short u) {
  return __uint_as_float(((unsigned int)u) << 16);
}

__device__ __forceinline__ void gload16(const void* g, void* l) {
  // async global->LDS, 16B per lane; LDS dest = wave-uniform base + lane*16
  __builtin_amdgcn_global_load_lds((const __attribute__((address_space(1))) void*)g,
                                   (__attribute__((address_space(3))) void*)l, 16, 0, 0);
}

// ---------------- unified prep kernel ----------------
// block = (32,8). Jobs by blockIdx.x:
//  [0,4096)    transpose in_proj_w  (1024x4096 -> 4096x1024 bf16)
//  [4096,4288) transpose x_proj_w   (2048x96   -> 96x2048  bf16)
//  [4288,4416) transpose dt_proj_w  (64x2048   -> 2048x64  bf16)
//  [4416,6464) transpose out_proj_w (2048x1024 -> 1024x2048 bf16)
//  [6464,8512) cast x fp32 -> bf16
//  [8512,8544) zero w3t pad rows 96..127
__global__ void prep_kernel(const float* __restrict__ in_proj_w, const float* __restrict__ x_proj_w,
                            const float* __restrict__ dt_proj_w,
                            const float* __restrict__ out_proj_w, const float* __restrict__ x,
                            unsigned short* __restrict__ w1t, unsigned short* __restrict__ w3t,
                            unsigned short* __restrict__ w4t, unsigned short* __restrict__ w5t,
                            unsigned short* __restrict__ xb) {
  const int bx = blockIdx.x;
  const int tx = threadIdx.x, ty = threadIdx.y;
  const int id = ty * 32 + tx;

  if (bx >= 6464) {
    if (bx < 8512) {  // cast x
      const int fid = (bx - 6464) * 256 + id;
      f32x4 v = ((const f32x4*)x)[fid];
      ushort4 o;
      o.x = f2bf(v.x); o.y = f2bf(v.y); o.z = f2bf(v.z); o.w = f2bf(v.w);
      ((ushort4*)xb)[fid] = o;
    } else {  // zero w3t pad rows [96,128)
      const int fid = (bx - 8512) * 256 + id;
      ((uint4*)(w3t + 96 * 2048))[fid] = (uint4){0, 0, 0, 0};
    }
    return;
  }

  const float* in;
  unsigned short* out;
  int R, C, rel, gx;
  if (bx < 4096) { in = in_proj_w; out = w1t; R = 1024; C = 4096; rel = bx; gx = 128; }
  else if (bx < 4288) { in = x_proj_w; out = w3t; R = 2048; C = 96; rel = bx - 4096; gx = 3; }
  else if (bx < 4416) { in = dt_proj_w; out = w4t; R = 64; C = 2048; rel = bx - 4288; gx = 64; }
  else { in = out_proj_w; out = w5t; R = 2048; C = 1024; rel = bx - 4416; gx = 32; }
  const int c0 = (rel % gx) * 32, r0 = (rel / gx) * 32;

  __shared__ float tile[32][33];
  for (int y = ty; y < 32; y += 8) tile[y][tx] = in[(size_t)(r0 + y) * C + c0 + tx];
  __syncthreads();
  for (int y = ty; y < 32; y += 8) out[(size_t)(c0 + y) * R + r0 + tx] = f2bf(tile[tx][y]);
}

// depthwise causal conv (4 taps) + silu, bf16 in/out, 4 timesteps per thread
__global__ void conv_silu_kernel(const unsigned short* __restrict__ xin,
                                 const float* __restrict__ cw, const float* __restrict__ cb,
                                 unsigned short* __restrict__ ub) {
  const int id = blockIdx.x * 256 + threadIdx.x;  // over 2048*512
  const int d = id & (DINNER - 1);
  const int t0 = (id >> 11) * 4;
  float xv[7];
#pragma unroll
  for (int j = 0; j < 7; j++) {
    int tt = t0 - 3 + j;
    xv[j] = (tt >= 0) ? bf2f(xin[(size_t)tt * DINNER + d]) : 0.f;
  }
  float w0 = cw[d], w1 = cw[DINNER + d], w2 = cw[2 * DINNER + d], w3 = cw[3 * DINNER + d];
  const float b = cb[d];
#pragma unroll
  for (int k = 0; k < 4; k++) {
    float acc = b + xv[k] * w0 + xv[k + 1] * w1 + xv[k + 2] * w2 + xv[k + 3] * w3;
    float s = acc / (1.f + __expf(-acc));
    ub[(size_t)(t0 + k) * DINNER + d] = f2bf(s);
  }
}

// ---------------- bf16 MFMA GEMM: C[M,N] = A[M,K] @ Bt[N,K]^T ----------------
// BMxBN tile, BK=64 double-buffered LDS, post-barrier prefetch, XOR bank
// swizzle on 16B k-chunks. 4 waves in 2x2, wave tile (BM/2)x(BN/2).
// EPI: 0 = store fp32 +bias, 3 = split-K partial store (z-indexed),
//      4 = G1 dual: col<DINNER -> bf16 xin ((ushort*)C); else silu->bf16 C2,
//      5 = softplus(+bias) -> bf16 C2 (stride N).
template <int EPI, int BM, int BN>
__global__ void gemm_bf16(const unsigned short* __restrict__ A,
                          const unsigned short* __restrict__ Bt, float* __restrict__ C,
                          unsigned short* __restrict__ C2, const float* __restrict__ bias, int M,
                          int N, int K, int KS) {
  constexpr int MI = BM / 32, NJ = BN / 32;
  __shared__ __align__(16) unsigned short lA[2][BM * 64];
  __shared__ __align__(16) unsigned short lB[2][BN * 64];
  const int tid = threadIdx.x;
  const int w = tid >> 6;
  const int lane = tid & 63;
  const int m0 = blockIdx.x * BM;
  const int n0 = blockIdx.y * BN;
  const int kbase = blockIdx.z * KS;
  const int lr = lane >> 3;                  // row within 8-row staging group
  const int srcoff = ((lane & 7) ^ lr) * 8;  // swizzled source chunk (elems)
  const int wm = (w & 1) * (BM / 2);
  const int wn = (w >> 1) * (BN / 2);
  const int ml = lane & 15;
  const int quad = lane >> 4;

  f32x4 acc[MI][NJ];
#pragma unroll
  for (int i = 0; i < MI; i++)
#pragma unroll
    for (int j = 0; j < NJ; j++) acc[i][j] = (f32x4){0.f, 0.f, 0.f, 0.f};

  const unsigned short* Ag = A + (size_t)m0 * K + kbase;
  const unsigned short* Bg = Bt + (size_t)n0 * K + kbase;

  const int niter = KS >> 6;
  auto stage = [&](int buf, int kk) {
#pragma unroll
    for (int c2 = 0; c2 < BM / 32; c2++) {
      const int row = w * (BM / 4) + c2 * 8 + lr;
      gload16(Ag + (size_t)row * K + kk + srcoff, &lA[buf][(w * (BM / 4) + c2 * 8) * 64]);
    }
#pragma unroll
    for (int c2 = 0; c2 < BN / 32; c2++) {
      const int row = w * (BN / 4) + c2 * 8 + lr;
      gload16(Bg + (size_t)row * K + kk + srcoff, &lB[buf][(w * (BN / 4) + c2 * 8) * 64]);
    }
  };

  stage(0, 0);
  for (int it = 0; it < niter; it++) {
    __syncthreads();
    if (it + 1 < niter) stage((it + 1) & 1, (it + 1) << 6);  // overlaps MFMA below
    const unsigned short* bufA = lA[it & 1];
    const unsigned short* bufB = lB[it & 1];
#pragma unroll
    for (int ks = 0; ks < 2; ks++) {
      short8 af[MI], bfr[NJ];
#pragma unroll
      for (int i = 0; i < MI; i++) {
        const int row = wm + i * 16 + ml;
        af[i] = *(const short8*)&bufA[row * 64 + ((ks * 4 + quad) ^ (ml & 7)) * 8];
      }
#pragma unroll
      for (int j = 0; j < NJ; j++) {
        const int row = wn + j * 16 + ml;
        bfr[j] = *(const short8*)&bufB[row * 64 + ((ks * 4 + quad) ^ (ml & 7)) * 8];
      }
#pragma unroll
      for (int i = 0; i < MI; i++)
#pragma unroll
        for (int j = 0; j < NJ; j++)
          acc[i][j] = __builtin_amdgcn_mfma_f32_16x16x32_bf16(af[i], bfr[j], acc[i][j], 0, 0, 0);
    }
  }

  float* Cp = (EPI == 3) ? C + (size_t)blockIdx.z * M * N : C;
#pragma unroll
  for (int i = 0; i < MI; i++) {
#pragma unroll
    for (int j = 0; j < NJ; j++) {
      const int col = n0 + wn + j * 16 + ml;
      float bv = (EPI == 3) ? 0.f : (bias ? bias[col] : 0.f);
#pragma unroll
      for (int r = 0; r < 4; r++) {
        const int row = m0 + wm + i * 16 + quad * 4 + r;
        float v = acc[i][j][r] + bv;
        if (EPI == 0 || EPI == 3) {
          Cp[(size_t)row * N + col] = v;
        } else if (EPI == 4) {
          if (col < DINNER) {
            ((unsigned short*)C)[(size_t)row * DINNER + col] = f2bf(v);
          } else {
            float s = v / (1.f + __expf(-v));
            C2[(size_t)row * DINNER + (col - DINNER)] = f2bf(s);
          }
        } else if (EPI == 5) {
          float sp = (v > 15.f) ? v : __logf(1.f + __expf(v));
          C2[(size_t)row * N + col] = f2bf(sp);
        }
      }
    }
  }
}

// sum 8 G3 partials -> dbc fp32; also emit dt slice (cols<64) as bf16
__global__ void reduce_dbc_kernel(const float* __restrict__ part, float* __restrict__ dbc,
                                  unsigned short* __restrict__ dtb) {
  const int id = blockIdx.x * 256 + threadIdx.x;  // 2048*128
  float s = 0.f;
#pragma unroll
  for (int z = 0; z < 8; z++) s += part[(size_t)z * (L_SEQ * NPROJ_PAD) + id];
  dbc[id] = s;
  const int col = id & 127;
  if (col < 64) dtb[(id >> 7) * 64 + col] = f2bf(s);
}

// ---------------- selective scan: shared phase bodies ----------------

__device__ __forceinline__ void scan_phase1(const unsigned short* db, const unsigned short* ub,
                                            const float* dbc, const float* A_log,
                                            unsigned short* P, unsigned short* Hz, int d, int c,
                                            float (&Bs)[TCH][NSTATE]) {
  float Ad[16], h[16], p[16];
#pragma unroll
  for (int n = 0; n < 16; n++) {
    Ad[n] = -__expf(A_log[d * 16 + n]);
    h[n] = 0.f;
    p[n] = 1.f;
  }
  __syncthreads();
#pragma unroll
  for (int t = 0; t < TCH; t++) {
    const int tt = c * TCH + t;
    float dl = bf2f(db[(size_t)tt * DINNER + d]);
    float uu = bf2f(ub[(size_t)tt * DINNER + d]);
    float du = dl * uu;
#pragma unroll
    for (int n = 0; n < 16; n++) {
      float dA = __expf(dl * Ad[n]);
      p[n] *= dA;
      h[n] = dA * h[n] + du * Bs[t][n];
    }
  }
#pragma unroll
  for (int n = 0; n < 16; n++) {
    P[(size_t)(c * 16 + n) * DINNER + d] = f2bf(p[n]);
    Hz[(size_t)(c * 16 + n) * DINNER + d] = f2bf(h[n]);
  }
}

__device__ __forceinline__ void scan_phase3(const unsigned short* db, const unsigned short* ub,
                                            const float* A_log, const float* Dv,
                                            const unsigned short* rsil, const unsigned short* H0,
                                            unsigned short* ygb, int d, int c,
                                            float (&Bs)[TCH][NSTATE], float (&Cs)[TCH][NSTATE]) {
  float Ad[16], h[16];
#pragma unroll
  for (int n = 0; n < 16; n++) {
    Ad[n] = -__expf(A_log[d * 16 + n]);
    h[n] = bf2f(H0[(size_t)(c * 16 + n) * DINNER + d]);
  }
  const float Dd = Dv[d];
#pragma unroll
  for (int t = 0; t < TCH; t++) {
    const int tt = c * TCH + t;
    float dl = bf2f(db[(size_t)tt * DINNER + d]);
    float uu = bf2f(ub[(size_t)tt * DINNER + d]);
    float rs = bf2f(rsil[(size_t)tt * DINNER + d]);
    float du = dl * uu;
    float y0 = 0.f, y1 = 0.f;
#pragma unroll
    for (int n = 0; n < 16; n++) {
      float dA = __expf(dl * Ad[n]);
      h[n] = dA * h[n] + du * Bs[t][n];
      if (n & 1) y1 += h[n] * Cs[t][n];
      else y0 += h[n] * Cs[t][n];
    }
    float yg = (y0 + y1 + uu * Dd) * rs;
    ygb[(size_t)tt * DINNER + d] = f2bf(yg);
  }
}

__device__ __forceinline__ void load_bc(const float* dbc, int c, float (&Bs)[TCH][NSTATE],
                                        float (&Cs)[TCH][NSTATE], int tid) {
  for (int idx = tid; idx < TCH * 2 * NSTATE; idx += 256) {
    int t = idx >> 5, q = idx & 31;
    float v = dbc[(size_t)(c * TCH + t) * NPROJ_PAD + DTRANK + q];
    if (q < 16) Bs[t][q] = v;
    else Cs[t][q - 16] = v;
  }
}

// ---- fused cooperative version (preferred) ----
__global__ void __launch_bounds__(256, 4)
scan_fused_kernel(const unsigned short* __restrict__ db, const unsigned short* __restrict__ ub,
                  const float* __restrict__ dbc, const float* __restrict__ A_log,
                  const float* __restrict__ Dv, const unsigned short* __restrict__ rsil,
                  unsigned short* __restrict__ P, unsigned short* __restrict__ Hz,
                  unsigned short* __restrict__ H0, unsigned short* __restrict__ ygb) {
  cg::grid_group grid = cg::this_grid();
  __shared__ float Bs[TCH][NSTATE];
  __shared__ float Cs[TCH][NSTATE];
  const int d = blockIdx.x * 256 + threadIdx.x;
  const int c = blockIdx.y;
  load_bc(dbc, c, Bs, Cs, threadIdx.x);
  scan_phase1(db, ub, dbc, A_log, P, Hz, d, c, Bs);
  grid.sync();
  const int gid = (blockIdx.y * gridDim.x + blockIdx.x) * 256 + threadIdx.x;
  if (gid < NSTATE * DINNER) {
    float hh = 0.f;
#pragma unroll 8
    for (int c2 = 0; c2 < NCH; c2++) {
      H0[(size_t)c2 * (NSTATE * DINNER) + gid] = f2bf(hh);
      hh = bf2f(P[(size_t)c2 * (NSTATE * DINNER) + gid]) * hh +
           bf2f(Hz[(size_t)c2 * (NSTATE * DINNER) + gid]);
    }
  }
  grid.sync();
  scan_phase3(db, ub, A_log, Dv, rsil, H0, ygb, d, c, Bs, Cs);
}

// ---- 3-kernel fallback (proven) ----
__global__ void scan1_kernel(const unsigned short* __restrict__ db,
                             const unsigned short* __restrict__ ub, const float* __restrict__ dbc,
                             const float* __restrict__ A_log, unsigned short* __restrict__ P,
                             unsigned short* __restrict__ Hz) {
  __shared__ float Bs[TCH][NSTATE];
  __shared__ float Cs[TCH][NSTATE];
  const int d = blockIdx.x * 256 + threadIdx.x;
  const int c = blockIdx.y;
  load_bc(dbc, c, Bs, Cs, threadIdx.x);
  scan_phase1(db, ub, dbc, A_log, P, Hz, d, c, Bs);
}

__global__ void scan_carry_kernel(const unsigned short* __restrict__ P,
                                  const unsigned short* __restrict__ Hz,
                                  unsigned short* __restrict__ H0) {
  const int id = blockIdx.x * 256 + threadIdx.x;  // 16*2048 (n,d) pairs
  float h = 0.f;
#pragma unroll 8
  for (int c = 0; c < NCH; c++) {
    H0[c * (NSTATE * DINNER) + id] = f2bf(h);
    h = bf2f(P[c * (NSTATE * DINNER) + id]) * h + bf2f(Hz[c * (NSTATE * DINNER) + id]);
  }
}

__global__ void scan2_kernel(const unsigned short* __restrict__ db,
                             const unsigned short* __restrict__ ub, const float* __restrict__ dbc,
                             const float* __restrict__ A_log, const float* __restrict__ Dv,
                             const unsigned short* __restrict__ rsil,
                             const unsigned short* __restrict__ H0,
                             unsigned short* __restrict__ ygb) {
  __shared__ float Bs[TCH][NSTATE];
  __shared__ float Cs[TCH][NSTATE];
  const int d = blockIdx.x * 256 + threadIdx.x;
  const int c = blockIdx.y;
  load_bc(dbc, c, Bs, Cs, threadIdx.x);
  __syncthreads();
  scan_phase3(db, ub, A_log, Dv, rsil, H0, ygb, d, c, Bs, Cs);
}

// ---------------- launch ----------------

extern "C" void kernel_launch(void* const* d_in, const int* in_sizes, int n_in, void* d_out,
                              int out_size, void* d_ws, size_t ws_size, hipStream_t stream) {
  const float* x = (const float*)d_in[0];
  const float* in_proj_w = (const float*)d_in[1];
  const float* in_proj_b = (const float*)d_in[2];
  const float* conv_w = (const float*)d_in[3];
  const float* conv_b = (const float*)d_in[4];
  const float* x_proj_w = (const float*)d_in[5];
  const float* dt_proj_w = (const float*)d_in[6];
  const float* dt_proj_b = (const float*)d_in[7];
  const float* A_log = (const float*)d_in[8];
  const float* Dvec = (const float*)d_in[9];
  const float* out_proj_w = (const float*)d_in[10];
  const float* out_proj_b = (const float*)d_in[11];
  float* out = (float*)d_out;
  char* ws = (char*)d_ws;
  (void)in_sizes; (void)n_in; (void)out_size; (void)ws_size;

  // workspace layout (MiB offsets), total ~90 MiB
  const size_t MB = 1048576;
  const size_t XB = 0;               // 2048x1024 bf16   4
  const size_t W1T = 4 * MB;         // 4096x1024 bf16   8
  const size_t XIN = 12 * MB;        // 2048x2048 bf16   8
  const size_t RSIL = 20 * MB;       // 2048x2048 bf16   8  (silu(res))
  const size_t UB = 28 * MB;         // 2048x2048 bf16   8
  const size_t W3T = 36 * MB;        // 128x2048 bf16  0.5
  const size_t DBC = W3T + 524288;   // 2048x128 fp32    1
  const size_t DTB = DBC + MB;       // 2048x64 bf16  0.25
  const size_t W4T = DTB + 262144;   // 2048x64 bf16  0.25
  const size_t DELTA = 38 * MB;      // 2048x2048 bf16   8
  const size_t YGB = 46 * MB;        // 2048x2048 bf16   8
  const size_t W5T = 54 * MB;        // 1024x2048 bf16   4
  const size_t G3P = 58 * MB;        // 8 x 1 MiB partials
  const size_t PB = 66 * MB;         // 128x16x2048 bf16 8
  const size_t HZB = 74 * MB;        // 8
  const size_t H0B = 82 * MB;        // 8

  // one prep kernel: 4 transposes + cast x + zero w3t pad
  prep_kernel<<<8544, dim3(32, 8), 0, stream>>>(
      in_proj_w, x_proj_w, dt_proj_w, out_proj_w, x, (unsigned short*)(ws + W1T),
      (unsigned short*)(ws + W3T), (unsigned short*)(ws + W4T), (unsigned short*)(ws + W5T),
      (unsigned short*)(ws + XB));

  // G1: [xin(bf16) | silu(res)(bf16)] = x @ in_proj_w + b  (M=2048,N=4096,K=1024)
  gemm_bf16<4, 128, 128><<<dim3(16, 32, 1), 256, 0, stream>>>(
      (const unsigned short*)(ws + XB), (const unsigned short*)(ws + W1T), (float*)(ws + XIN),
      (unsigned short*)(ws + RSIL), in_proj_b, 2048, 4096, 1024, 1024);

  // conv + silu -> u bf16 (4 timesteps/thread)
  conv_silu_kernel<<<(L_SEQ * DINNER / 4) / 256, 256, 0, stream>>>(
      (const unsigned short*)(ws + XIN), conv_w, conv_b, (unsigned short*)(ws + UB));

  // G3: dbc partials (M=2048,N=128,K=2048, split-K=8, 64-row tiles)
  gemm_bf16<3, 64, 128><<<dim3(32, 1, 8), 256, 0, stream>>>(
      (const unsigned short*)(ws + UB), (const unsigned short*)(ws + W3T), (float*)(ws + G3P),
      nullptr, nullptr, 2048, NPROJ_PAD, 2048, 256);
  reduce_dbc_kernel<<<(L_SEQ * NPROJ_PAD) / 256, 256, 0, stream>>>(
      (const float*)(ws + G3P), (float*)(ws + DBC), (unsigned short*)(ws + DTB));

  // G5: delta = softplus(dt @ dt_proj_w + b) -> bf16  (M=2048,N=2048,K=64)
  gemm_bf16<5, 128, 128><<<dim3(16, 16, 1), 256, 0, stream>>>(
      (const unsigned short*)(ws + DTB), (const unsigned short*)(ws + W4T), nullptr,
      (unsigned short*)(ws + DELTA), dt_proj_b, 2048, 2048, 64, 64);

  // fused selective scan: cooperative if the runtime accepts it, else 3-kernel
  {
    const unsigned short* dbp = (const unsigned short*)(ws + DELTA);
    const unsigned short* ubp = (const unsigned short*)(ws + UB);
    const float* dbcp = (const float*)(ws + DBC);
    const float* alogp = A_log;
    const float* dvp = Dvec;
    const unsigned short* rsilp = (const unsigned short*)(ws + RSIL);
    unsigned short* pbp = (unsigned short*)(ws + PB);
    unsigned short* hzp = (unsigned short*)(ws + HZB);
    unsigned short* h0p = (unsigned short*)(ws + H0B);
    unsigned short* ygp = (unsigned short*)(ws + YGB);
    void* sargs[] = {(void*)&dbp, (void*)&ubp, (void*)&dbcp, (void*)&alogp, (void*)&dvp,
                     (void*)&rsilp, (void*)&pbp, (void*)&hzp, (void*)&h0p, (void*)&ygp};
    hipError_t cerr = hipLaunchCooperativeKernel((void*)scan_fused_kernel,
                                                 dim3(DINNER / 256, NCH), dim3(256), sargs, 0,
                                                 stream);
    if (cerr != hipSuccess) {
      const dim3 sgrid(DINNER / 256, NCH);
      scan1_kernel<<<sgrid, 256, 0, stream>>>(dbp, ubp, dbcp, alogp, pbp, hzp);
      scan_carry_kernel<<<(NSTATE * DINNER) / 256, 256, 0, stream>>>(pbp, hzp, h0p);
      scan2_kernel<<<sgrid, 256, 0, stream>>>(dbp, ubp, dbcp, alogp, dvp, rsilp, h0p, ygp);
    }
  }

  // G2: out = yg @ out_proj_w + b  (M=2048,N=1024,K=2048, 64x64 tiles, direct)
  gemm_bf16<0, 64, 64><<<dim3(32, 16, 1), 256, 0, stream>>>(
      (const unsigned short*)(ws + YGB), (const unsigned short*)(ws + W5T), out, nullptr,
      out_proj_b, 2048, 1024, 2048, 2048);
}

// Round 9
// 227.304 us; speedup vs baseline: 2.3282x; 2.3282x over previous
//
#include <hip/hip_runtime.h>

// Mamba block fused pipeline, MI355X gfx950.
// B=1, L=2048, D_MODEL=1024, D_INNER=2048, D_CONV=4, DT_RANK=64, D_STATE=16.
//
// R9: cooperative fused scan REMOVED (R8 measured grid.sync at ~300us across
// 8 XCDs — global spin barrier; 3 separate dispatches are the cheap barrier).
// Keeps R8's wins: xin stored bf16 by G1 (conv reads bf16, 4 t/thread),
// all-bf16 intermediate streams, partial-buffer split-K (no atomics).

#define L_SEQ 2048
#define DMODEL 1024
#define DINNER 2048
#define NSTATE 16
#define DTRANK 64
#define NPROJ_PAD 128
#define NCH 128
#define TCH 16

typedef __attribute__((ext_vector_type(8))) short short8;
typedef __attribute__((ext_vector_type(4))) float f32x4;

__device__ __forceinline__ unsigned short f2bf(float f) {
  unsigned int u = __float_as_uint(f);
  u += 0x7FFFu + ((u >> 16) & 1u);  // round-to-nearest-even
  return (unsigned short)(u >> 16);
}
__device__ __forceinline__ float bf2f(unsigned short u) {
  return __uint_as_float(((unsigned int)u) << 16);
}

__device__ __forceinline__ void gload16(const void* g, void* l) {
  // async global->LDS, 16B per lane; LDS dest = wave-uniform base + lane*16
  __builtin_amdgcn_global_load_lds((const __attribute__((address_space(1))) void*)g,
                                   (__attribute__((address_space(3))) void*)l, 16, 0, 0);
}

// ---------------- unified prep kernel ----------------
// block = (32,8). Jobs by blockIdx.x:
//  [0,4096)    transpose in_proj_w  (1024x4096 -> 4096x1024 bf16)
//  [4096,4288) transpose x_proj_w   (2048x96   -> 96x2048  bf16)
//  [4288,4416) transpose dt_proj_w  (64x2048   -> 2048x64  bf16)
//  [4416,6464) transpose out_proj_w (2048x1024 -> 1024x2048 bf16)
//  [6464,8512) cast x fp32 -> bf16
//  [8512,8544) zero w3t pad rows 96..127
__global__ void prep_kernel(const float* __restrict__ in_proj_w, const float* __restrict__ x_proj_w,
                            const float* __restrict__ dt_proj_w,
                            const float* __restrict__ out_proj_w, const float* __restrict__ x,
                            unsigned short* __restrict__ w1t, unsigned short* __restrict__ w3t,
                            unsigned short* __restrict__ w4t, unsigned short* __restrict__ w5t,
                            unsigned short* __restrict__ xb) {
  const int bx = blockIdx.x;
  const int tx = threadIdx.x, ty = threadIdx.y;
  const int id = ty * 32 + tx;

  if (bx >= 6464) {
    if (bx < 8512) {  // cast x
      const int fid = (bx - 6464) * 256 + id;
      f32x4 v = ((const f32x4*)x)[fid];
      ushort4 o;
      o.x = f2bf(v.x); o.y = f2bf(v.y); o.z = f2bf(v.z); o.w = f2bf(v.w);
      ((ushort4*)xb)[fid] = o;
    } else {  // zero w3t pad rows [96,128)
      const int fid = (bx - 8512) * 256 + id;
      ((uint4*)(w3t + 96 * 2048))[fid] = (uint4){0, 0, 0, 0};
    }
    return;
  }

  const float* in;
  unsigned short* out;
  int R, C, rel, gx;
  if (bx < 4096) { in = in_proj_w; out = w1t; R = 1024; C = 4096; rel = bx; gx = 128; }
  else if (bx < 4288) { in = x_proj_w; out = w3t; R = 2048; C = 96; rel = bx - 4096; gx = 3; }
  else if (bx < 4416) { in = dt_proj_w; out = w4t; R = 64; C = 2048; rel = bx - 4288; gx = 64; }
  else { in = out_proj_w; out = w5t; R = 2048; C = 1024; rel = bx - 4416; gx = 32; }
  const int c0 = (rel % gx) * 32, r0 = (rel / gx) * 32;

  __shared__ float tile[32][33];
  for (int y = ty; y < 32; y += 8) tile[y][tx] = in[(size_t)(r0 + y) * C + c0 + tx];
  __syncthreads();
  for (int y = ty; y < 32; y += 8) out[(size_t)(c0 + y) * R + r0 + tx] = f2bf(tile[tx][y]);
}

// depthwise causal conv (4 taps) + silu, bf16 in/out, 4 timesteps per thread
__global__ void conv_silu_kernel(const unsigned short* __restrict__ xin,
                                 const float* __restrict__ cw, const float* __restrict__ cb,
                                 unsigned short* __restrict__ ub) {
  const int id = blockIdx.x * 256 + threadIdx.x;  // over 2048*512
  const int d = id & (DINNER - 1);
  const int t0 = (id >> 11) * 4;
  float xv[7];
#pragma unroll
  for (int j = 0; j < 7; j++) {
    int tt = t0 - 3 + j;
    xv[j] = (tt >= 0) ? bf2f(xin[(size_t)tt * DINNER + d]) : 0.f;
  }
  float w0 = cw[d], w1 = cw[DINNER + d], w2 = cw[2 * DINNER + d], w3 = cw[3 * DINNER + d];
  const float b = cb[d];
#pragma unroll
  for (int k = 0; k < 4; k++) {
    float acc = b + xv[k] * w0 + xv[k + 1] * w1 + xv[k + 2] * w2 + xv[k + 3] * w3;
    float s = acc / (1.f + __expf(-acc));
    ub[(size_t)(t0 + k) * DINNER + d] = f2bf(s);
  }
}

// ---------------- bf16 MFMA GEMM: C[M,N] = A[M,K] @ Bt[N,K]^T ----------------
// BMxBN tile, BK=64 double-buffered LDS, post-barrier prefetch, XOR bank
// swizzle on 16B k-chunks. 4 waves in 2x2, wave tile (BM/2)x(BN/2).
// EPI: 0 = store fp32 +bias, 3 = split-K partial store (z-indexed),
//      4 = G1 dual: col<DINNER -> bf16 xin ((ushort*)C); else silu->bf16 C2,
//      5 = softplus(+bias) -> bf16 C2 (stride N).
template <int EPI, int BM, int BN>
__global__ void gemm_bf16(const unsigned short* __restrict__ A,
                          const unsigned short* __restrict__ Bt, float* __restrict__ C,
                          unsigned short* __restrict__ C2, const float* __restrict__ bias, int M,
                          int N, int K, int KS) {
  constexpr int MI = BM / 32, NJ = BN / 32;
  __shared__ __align__(16) unsigned short lA[2][BM * 64];
  __shared__ __align__(16) unsigned short lB[2][BN * 64];
  const int tid = threadIdx.x;
  const int w = tid >> 6;
  const int lane = tid & 63;
  const int m0 = blockIdx.x * BM;
  const int n0 = blockIdx.y * BN;
  const int kbase = blockIdx.z * KS;
  const int lr = lane >> 3;                  // row within 8-row staging group
  const int srcoff = ((lane & 7) ^ lr) * 8;  // swizzled source chunk (elems)
  const int wm = (w & 1) * (BM / 2);
  const int wn = (w >> 1) * (BN / 2);
  const int ml = lane & 15;
  const int quad = lane >> 4;

  f32x4 acc[MI][NJ];
#pragma unroll
  for (int i = 0; i < MI; i++)
#pragma unroll
    for (int j = 0; j < NJ; j++) acc[i][j] = (f32x4){0.f, 0.f, 0.f, 0.f};

  const unsigned short* Ag = A + (size_t)m0 * K + kbase;
  const unsigned short* Bg = Bt + (size_t)n0 * K + kbase;

  const int niter = KS >> 6;
  auto stage = [&](int buf, int kk) {
#pragma unroll
    for (int c2 = 0; c2 < BM / 32; c2++) {
      const int row = w * (BM / 4) + c2 * 8 + lr;
      gload16(Ag + (size_t)row * K + kk + srcoff, &lA[buf][(w * (BM / 4) + c2 * 8) * 64]);
    }
#pragma unroll
    for (int c2 = 0; c2 < BN / 32; c2++) {
      const int row = w * (BN / 4) + c2 * 8 + lr;
      gload16(Bg + (size_t)row * K + kk + srcoff, &lB[buf][(w * (BN / 4) + c2 * 8) * 64]);
    }
  };

  stage(0, 0);
  for (int it = 0; it < niter; it++) {
    __syncthreads();
    if (it + 1 < niter) stage((it + 1) & 1, (it + 1) << 6);  // overlaps MFMA below
    const unsigned short* bufA = lA[it & 1];
    const unsigned short* bufB = lB[it & 1];
#pragma unroll
    for (int ks = 0; ks < 2; ks++) {
      short8 af[MI], bfr[NJ];
#pragma unroll
      for (int i = 0; i < MI; i++) {
        const int row = wm + i * 16 + ml;
        af[i] = *(const short8*)&bufA[row * 64 + ((ks * 4 + quad) ^ (ml & 7)) * 8];
      }
#pragma unroll
      for (int j = 0; j < NJ; j++) {
        const int row = wn + j * 16 + ml;
        bfr[j] = *(const short8*)&bufB[row * 64 + ((ks * 4 + quad) ^ (ml & 7)) * 8];
      }
#pragma unroll
      for (int i = 0; i < MI; i++)
#pragma unroll
        for (int j = 0; j < NJ; j++)
          acc[i][j] = __builtin_amdgcn_mfma_f32_16x16x32_bf16(af[i], bfr[j], acc[i][j], 0, 0, 0);
    }
  }

  float* Cp = (EPI == 3) ? C + (size_t)blockIdx.z * M * N : C;
#pragma unroll
  for (int i = 0; i < MI; i++) {
#pragma unroll
    for (int j = 0; j < NJ; j++) {
      const int col = n0 + wn + j * 16 + ml;
      float bv = (EPI == 3) ? 0.f : (bias ? bias[col] : 0.f);
#pragma unroll
      for (int r = 0; r < 4; r++) {
        const int row = m0 + wm + i * 16 + quad * 4 + r;
        float v = acc[i][j][r] + bv;
        if (EPI == 0 || EPI == 3) {
          Cp[(size_t)row * N + col] = v;
        } else if (EPI == 4) {
          if (col < DINNER) {
            ((unsigned short*)C)[(size_t)row * DINNER + col] = f2bf(v);
          } else {
            float s = v / (1.f + __expf(-v));
            C2[(size_t)row * DINNER + (col - DINNER)] = f2bf(s);
          }
        } else if (EPI == 5) {
          float sp = (v > 15.f) ? v : __logf(1.f + __expf(v));
          C2[(size_t)row * N + col] = f2bf(sp);
        }
      }
    }
  }
}

// sum 8 G3 partials -> dbc fp32; also emit dt slice (cols<64) as bf16
__global__ void reduce_dbc_kernel(const float* __restrict__ part, float* __restrict__ dbc,
                                  unsigned short* __restrict__ dtb) {
  const int id = blockIdx.x * 256 + threadIdx.x;  // 2048*128
  float s = 0.f;
#pragma unroll
  for (int z = 0; z < 8; z++) s += part[(size_t)z * (L_SEQ * NPROJ_PAD) + id];
  dbc[id] = s;
  const int col = id & 127;
  if (col < 64) dtb[(id >> 7) * 64 + col] = f2bf(s);
}

// ---------------- selective scan (3-kernel, proven) ----------------

__device__ __forceinline__ void load_bc(const float* dbc, int c, float (&Bs)[TCH][NSTATE],
                                        float (&Cs)[TCH][NSTATE], int tid) {
  for (int idx = tid; idx < TCH * 2 * NSTATE; idx += 256) {
    int t = idx >> 5, q = idx & 31;
    float v = dbc[(size_t)(c * TCH + t) * NPROJ_PAD + DTRANK + q];
    if (q < 16) Bs[t][q] = v;
    else Cs[t][q - 16] = v;
  }
}

__global__ void scan1_kernel(const unsigned short* __restrict__ db,
                             const unsigned short* __restrict__ ub, const float* __restrict__ dbc,
                             const float* __restrict__ A_log, unsigned short* __restrict__ P,
                             unsigned short* __restrict__ Hz) {
  __shared__ float Bs[TCH][NSTATE];
  __shared__ float Cs[TCH][NSTATE];
  const int d = blockIdx.x * 256 + threadIdx.x;
  const int c = blockIdx.y;
  load_bc(dbc, c, Bs, Cs, threadIdx.x);
  float Ad[16], h[16], p[16];
#pragma unroll
  for (int n = 0; n < 16; n++) {
    Ad[n] = -__expf(A_log[d * 16 + n]);
    h[n] = 0.f;
    p[n] = 1.f;
  }
  __syncthreads();
#pragma unroll
  for (int t = 0; t < TCH; t++) {
    const int tt = c * TCH + t;
    float dl = bf2f(db[(size_t)tt * DINNER + d]);
    float uu = bf2f(ub[(size_t)tt * DINNER + d]);
    float du = dl * uu;
#pragma unroll
    for (int n = 0; n < 16; n++) {
      float dA = __expf(dl * Ad[n]);
      p[n] *= dA;
      h[n] = dA * h[n] + du * Bs[t][n];
    }
  }
#pragma unroll
  for (int n = 0; n < 16; n++) {
    P[(size_t)(c * 16 + n) * DINNER + d] = f2bf(p[n]);
    Hz[(size_t)(c * 16 + n) * DINNER + d] = f2bf(h[n]);
  }
}

__global__ void scan_carry_kernel(const unsigned short* __restrict__ P,
                                  const unsigned short* __restrict__ Hz,
                                  unsigned short* __restrict__ H0) {
  const int id = blockIdx.x * 256 + threadIdx.x;  // 16*2048 (n,d) pairs
  float h = 0.f;
#pragma unroll 8
  for (int c = 0; c < NCH; c++) {
    H0[c * (NSTATE * DINNER) + id] = f2bf(h);
    h = bf2f(P[c * (NSTATE * DINNER) + id]) * h + bf2f(Hz[c * (NSTATE * DINNER) + id]);
  }
}

__global__ void scan2_kernel(const unsigned short* __restrict__ db,
                             const unsigned short* __restrict__ ub, const float* __restrict__ dbc,
                             const float* __restrict__ A_log, const float* __restrict__ Dv,
                             const unsigned short* __restrict__ rsil,
                             const unsigned short* __restrict__ H0,
                             unsigned short* __restrict__ ygb) {
  __shared__ float Bs[TCH][NSTATE];
  __shared__ float Cs[TCH][NSTATE];
  const int d = blockIdx.x * 256 + threadIdx.x;
  const int c = blockIdx.y;
  load_bc(dbc, c, Bs, Cs, threadIdx.x);
  float Ad[16], h[16];
#pragma unroll
  for (int n = 0; n < 16; n++) {
    Ad[n] = -__expf(A_log[d * 16 + n]);
    h[n] = bf2f(H0[(size_t)(c * 16 + n) * DINNER + d]);
  }
  const float Dd = Dv[d];
  __syncthreads();
#pragma unroll
  for (int t = 0; t < TCH; t++) {
    const int tt = c * TCH + t;
    float dl = bf2f(db[(size_t)tt * DINNER + d]);
    float uu = bf2f(ub[(size_t)tt * DINNER + d]);
    float rs = bf2f(rsil[(size_t)tt * DINNER + d]);
    float du = dl * uu;
    float y0 = 0.f, y1 = 0.f;
#pragma unroll
    for (int n = 0; n < 16; n++) {
      float dA = __expf(dl * Ad[n]);
      h[n] = dA * h[n] + du * Bs[t][n];
      if (n & 1) y1 += h[n] * Cs[t][n];
      else y0 += h[n] * Cs[t][n];
    }
    float yg = (y0 + y1 + uu * Dd) * rs;
    ygb[(size_t)tt * DINNER + d] = f2bf(yg);
  }
}

// ---------------- launch ----------------

extern "C" void kernel_launch(void* const* d_in, const int* in_sizes, int n_in, void* d_out,
                              int out_size, void* d_ws, size_t ws_size, hipStream_t stream) {
  const float* x = (const float*)d_in[0];
  const float* in_proj_w = (const float*)d_in[1];
  const float* in_proj_b = (const float*)d_in[2];
  const float* conv_w = (const float*)d_in[3];
  const float* conv_b = (const float*)d_in[4];
  const float* x_proj_w = (const float*)d_in[5];
  const float* dt_proj_w = (const float*)d_in[6];
  const float* dt_proj_b = (const float*)d_in[7];
  const float* A_log = (const float*)d_in[8];
  const float* Dvec = (const float*)d_in[9];
  const float* out_proj_w = (const float*)d_in[10];
  const float* out_proj_b = (const float*)d_in[11];
  float* out = (float*)d_out;
  char* ws = (char*)d_ws;
  (void)in_sizes; (void)n_in; (void)out_size; (void)ws_size;

  // workspace layout (MiB offsets), total ~90 MiB
  const size_t MB = 1048576;
  const size_t XB = 0;               // 2048x1024 bf16   4
  const size_t W1T = 4 * MB;         // 4096x1024 bf16   8
  const size_t XIN = 12 * MB;        // 2048x2048 bf16   8
  const size_t RSIL = 20 * MB;       // 2048x2048 bf16   8  (silu(res))
  const size_t UB = 28 * MB;         // 2048x2048 bf16   8
  const size_t W3T = 36 * MB;        // 128x2048 bf16  0.5
  const size_t DBC = W3T + 524288;   // 2048x128 fp32    1
  const size_t DTB = DBC + MB;       // 2048x64 bf16  0.25
  const size_t W4T = DTB + 262144;   // 2048x64 bf16  0.25
  const size_t DELTA = 38 * MB;      // 2048x2048 bf16   8
  const size_t YGB = 46 * MB;        // 2048x2048 bf16   8
  const size_t W5T = 54 * MB;        // 1024x2048 bf16   4
  const size_t G3P = 58 * MB;        // 8 x 1 MiB partials
  const size_t PB = 66 * MB;         // 128x16x2048 bf16 8
  const size_t HZB = 74 * MB;        // 8
  const size_t H0B = 82 * MB;        // 8

  // one prep kernel: 4 transposes + cast x + zero w3t pad
  prep_kernel<<<8544, dim3(32, 8), 0, stream>>>(
      in_proj_w, x_proj_w, dt_proj_w, out_proj_w, x, (unsigned short*)(ws + W1T),
      (unsigned short*)(ws + W3T), (unsigned short*)(ws + W4T), (unsigned short*)(ws + W5T),
      (unsigned short*)(ws + XB));

  // G1: [xin(bf16) | silu(res)(bf16)] = x @ in_proj_w + b  (M=2048,N=4096,K=1024)
  gemm_bf16<4, 128, 128><<<dim3(16, 32, 1), 256, 0, stream>>>(
      (const unsigned short*)(ws + XB), (const unsigned short*)(ws + W1T), (float*)(ws + XIN),
      (unsigned short*)(ws + RSIL), in_proj_b, 2048, 4096, 1024, 1024);

  // conv + silu -> u bf16 (4 timesteps/thread)
  conv_silu_kernel<<<(L_SEQ * DINNER / 4) / 256, 256, 0, stream>>>(
      (const unsigned short*)(ws + XIN), conv_w, conv_b, (unsigned short*)(ws + UB));

  // G3: dbc partials (M=2048,N=128,K=2048, split-K=8, 64-row tiles)
  gemm_bf16<3, 64, 128><<<dim3(32, 1, 8), 256, 0, stream>>>(
      (const unsigned short*)(ws + UB), (const unsigned short*)(ws + W3T), (float*)(ws + G3P),
      nullptr, nullptr, 2048, NPROJ_PAD, 2048, 256);
  reduce_dbc_kernel<<<(L_SEQ * NPROJ_PAD) / 256, 256, 0, stream>>>(
      (const float*)(ws + G3P), (float*)(ws + DBC), (unsigned short*)(ws + DTB));

  // G5: delta = softplus(dt @ dt_proj_w + b) -> bf16  (M=2048,N=2048,K=64)
  gemm_bf16<5, 128, 128><<<dim3(16, 16, 1), 256, 0, stream>>>(
      (const unsigned short*)(ws + DTB), (const unsigned short*)(ws + W4T), nullptr,
      (unsigned short*)(ws + DELTA), dt_proj_b, 2048, 2048, 64, 64);

  // selective scan: 3 dispatches (dispatch boundary = the cheap global barrier)
  {
    const unsigned short* dbp = (const unsigned short*)(ws + DELTA);
    const unsigned short* ubp = (const unsigned short*)(ws + UB);
    const float* dbcp = (const float*)(ws + DBC);
    const unsigned short* rsilp = (const unsigned short*)(ws + RSIL);
    unsigned short* pbp = (unsigned short*)(ws + PB);
    unsigned short* hzp = (unsigned short*)(ws + HZB);
    unsigned short* h0p = (unsigned short*)(ws + H0B);
    unsigned short* ygp = (unsigned short*)(ws + YGB);
    const dim3 sgrid(DINNER / 256, NCH);
    scan1_kernel<<<sgrid, 256, 0, stream>>>(dbp, ubp, dbcp, A_log, pbp, hzp);
    scan_carry_kernel<<<(NSTATE * DINNER) / 256, 256, 0, stream>>>(pbp, hzp, h0p);
    scan2_kernel<<<sgrid, 256, 0, stream>>>(dbp, ubp, dbcp, A_log, Dvec, rsilp, h0p, ygp);
  }

  // G2: out = yg @ out_proj_w + b  (M=2048,N=1024,K=2048, 64x64 tiles, direct)
  gemm_bf16<0, 64, 64><<<dim3(32, 16, 1), 256, 0, stream>>>(
      (const unsigned short*)(ws + YGB), (const unsigned short*)(ws + W5T), out, nullptr,
      out_proj_b, 2048, 1024, 2048, 2048);
}